// Round 1
// baseline (2571.690 us; speedup 1.0000x reference)
//
#include <hip/hip_runtime.h>

constexpr int D_ = 64;
constexpr int NN = 100000;
constexpr int NE = 1600000;

// ---- degree: one atomicAdd per edge endpoint (flat edges array = all endpoints)
__global__ __launch_bounds__(256) void k_degree(const int* __restrict__ ef,
                                                float* __restrict__ deg, int n) {
  int i = blockIdx.x * 256 + threadIdx.x;
  if (i < n) atomicAdd(deg + ef[i], 1.0f);
}

// ---- msg = h @ W + b ; one wave per row, lane j owns column j, W column in 64 VGPRs
__global__ __launch_bounds__(256) void k_gemm(const float* __restrict__ h,
                                              const float* __restrict__ W,
                                              const float* __restrict__ b,
                                              float* __restrict__ out, int nrows) {
  const int lane = threadIdx.x & 63;
  const int wid = (blockIdx.x * 256 + threadIdx.x) >> 6;
  const int nw = (gridDim.x * 256) >> 6;
  float w[64];
#pragma unroll
  for (int k = 0; k < 64; ++k) w[k] = W[k * 64 + lane];
  const float bias = b[lane];
  for (int r = wid; r < nrows; r += nw) {
    const float4* hr = reinterpret_cast<const float4*>(h + (size_t)r * 64);
    float acc = bias;
#pragma unroll
    for (int k4 = 0; k4 < 16; ++k4) {
      float4 hv = hr[k4];  // wave-uniform address -> broadcast, 1 line
      acc = fmaf(hv.x, w[4 * k4 + 0], acc);
      acc = fmaf(hv.y, w[4 * k4 + 1], acc);
      acc = fmaf(hv.z, w[4 * k4 + 2], acc);
      acc = fmaf(hv.w, w[4 * k4 + 3], acc);
    }
    out[(size_t)r * 64 + lane] = acc;
  }
}

// ---- scatter: per edge, both directions, 64-lane coalesced atomicAdd rows
__global__ __launch_bounds__(256) void k_scatter(const float* __restrict__ msg,
                                                 const int* __restrict__ edges,
                                                 float* __restrict__ agg, int ne) {
  const int lane = threadIdx.x & 63;
  const int wid = (blockIdx.x * 256 + threadIdx.x) >> 6;
  const int nw = (gridDim.x * 256) >> 6;
  for (int e = wid; e < ne; e += nw) {
    const int s = edges[2 * e];
    const int d = edges[2 * e + 1];
    const float ms = msg[(size_t)s * 64 + lane];
    const float md = msg[(size_t)d * 64 + lane];
    atomicAdd(agg + (size_t)d * 64 + lane, ms);
    atomicAdd(agg + (size_t)s * 64 + lane, md);
  }
}

// ---- out = h @ W + b + agg/deg ; optional fused LayerNorm + ReLU
template <bool LN>
__global__ __launch_bounds__(256) void k_gemm_out(const float* __restrict__ h,
                                                  const float* __restrict__ W,
                                                  const float* __restrict__ b,
                                                  const float* __restrict__ agg,
                                                  const float* __restrict__ deg,
                                                  const float* __restrict__ gamma,
                                                  const float* __restrict__ beta,
                                                  float* __restrict__ out, int nrows) {
  const int lane = threadIdx.x & 63;
  const int wid = (blockIdx.x * 256 + threadIdx.x) >> 6;
  const int nw = (gridDim.x * 256) >> 6;
  float w[64];
#pragma unroll
  for (int k = 0; k < 64; ++k) w[k] = W[k * 64 + lane];
  const float bias = b[lane];
  float gm = 1.0f, bt = 0.0f;
  if (LN) { gm = gamma[lane]; bt = beta[lane]; }
  for (int r = wid; r < nrows; r += nw) {
    const float4* hr = reinterpret_cast<const float4*>(h + (size_t)r * 64);
    float acc = bias;
#pragma unroll
    for (int k4 = 0; k4 < 16; ++k4) {
      float4 hv = hr[k4];
      acc = fmaf(hv.x, w[4 * k4 + 0], acc);
      acc = fmaf(hv.y, w[4 * k4 + 1], acc);
      acc = fmaf(hv.z, w[4 * k4 + 2], acc);
      acc = fmaf(hv.w, w[4 * k4 + 3], acc);
    }
    const float rdeg = 1.0f / fmaxf(deg[r], 1.0f);
    float val = fmaf(agg[(size_t)r * 64 + lane], rdeg, acc);
    if (LN) {
      float s = val;
#pragma unroll
      for (int off = 32; off > 0; off >>= 1) s += __shfl_xor(s, off, 64);
      const float mu = s * (1.0f / 64.0f);
      const float dv = val - mu;
      float v2 = dv * dv;
#pragma unroll
      for (int off = 32; off > 0; off >>= 1) v2 += __shfl_xor(v2, off, 64);
      const float var = v2 * (1.0f / 64.0f);
      val = fmaxf(fmaf(dv * rsqrtf(var + 1e-5f), gm, bt), 0.0f);
    }
    out[(size_t)r * 64 + lane] = val;
  }
}

extern "C" void kernel_launch(void* const* d_in, const int* in_sizes, int n_in,
                              void* d_out, int out_size, void* d_ws, size_t ws_size,
                              hipStream_t stream) {
  const float* vert = (const float*)d_in[0];
  const int* edges = (const int*)d_in[1];
  const float* W0 = (const float*)d_in[2];
  const float* b0 = (const float*)d_in[3];
  const float* W1 = (const float*)d_in[4];
  const float* b1 = (const float*)d_in[5];
  const float* lng = (const float*)d_in[6];
  const float* lnb = (const float*)d_in[7];
  float* out = (float*)d_out;

  const size_t HB = (size_t)NN * D_ * sizeof(float);  // 25.6 MB
  float* agg = (float*)d_ws;
  float* hbuf = (float*)((char*)d_ws + HB);
  float* deg = (float*)((char*)d_ws + 2 * HB);

  hipMemsetAsync(deg, 0, NN * sizeof(float), stream);
  k_degree<<<(2 * NE + 255) / 256, 256, 0, stream>>>(edges, deg, 2 * NE);

  const int GB = 2048;  // gemm blocks (8192 waves, ~12 rows each -> W regs amortized)
  const int SB = 4096;  // scatter blocks

  for (int l = 0; l < 3; ++l) {
    const float* hcur = (l == 0) ? vert : hbuf;
    float* msg = out;  // d_out doubles as msg scratch; dead before final write
    k_gemm<<<GB, 256, 0, stream>>>(hcur, W1 + l * 4096, b1 + l * 64, msg, NN);
    hipMemsetAsync(agg, 0, HB, stream);
    k_scatter<<<SB, 256, 0, stream>>>(msg, edges, agg, NE);
    if (l < 2) {
      k_gemm_out<true><<<GB, 256, 0, stream>>>(hcur, W0 + l * 4096, b0 + l * 64,
                                               agg, deg, lng + l * 64, lnb + l * 64,
                                               hbuf, NN);
    } else {
      k_gemm_out<false><<<GB, 256, 0, stream>>>(hcur, W0 + l * 4096, b0 + l * 64,
                                                agg, deg, nullptr, nullptr, out, NN);
    }
  }
}

// Round 2
// 1438.156 us; speedup vs baseline: 1.7882x; 1.7882x over previous
//
#include <hip/hip_runtime.h>

constexpr int D_ = 64;
constexpr int NN = 100000;
constexpr int NE = 1600000;

// ---- count endpoint occurrences (flat edges = 2*NE node ids)
__global__ __launch_bounds__(256) void k_count(const int* __restrict__ ef,
                                               int* __restrict__ cnt, int n) {
  int i = blockIdx.x * 256 + threadIdx.x;
  if (i < n) atomicAdd(cnt + ef[i], 1);
}

// ---- single-workgroup exclusive prefix scan over NN counts -> offs[0..NN]
__global__ __launch_bounds__(1024) void k_scan(const int* __restrict__ cnt,
                                               int* __restrict__ offs, int n) {
  __shared__ int sd[1024];
  __shared__ int running;
  const int tid = threadIdx.x;
  if (tid == 0) running = 0;
  __syncthreads();
  for (int base = 0; base < n; base += 1024) {
    int i = base + tid;
    int v = (i < n) ? cnt[i] : 0;
    sd[tid] = v;
    __syncthreads();
    for (int off = 1; off < 1024; off <<= 1) {
      int t = (tid >= off) ? sd[tid - off] : 0;
      __syncthreads();
      sd[tid] += t;
      __syncthreads();
    }
    int ex = running + sd[tid] - v;  // running last written before prev-iter barrier
    if (i < n) offs[i] = ex;
    int tot = sd[1023];
    __syncthreads();
    if (tid == 0) running += tot;
    __syncthreads();
  }
  if (tid == 0) offs[n] = running;
}

// ---- fill neighbor lists: for each edge, d's list gets s and s's list gets d
__global__ __launch_bounds__(256) void k_fill(const int* __restrict__ edges,
                                              const int* __restrict__ offs,
                                              int* __restrict__ cnt,
                                              int* __restrict__ nbr, int ne) {
  int e = blockIdx.x * 256 + threadIdx.x;
  if (e < ne) {
    int s = edges[2 * e];
    int d = edges[2 * e + 1];
    int pd = atomicAdd(cnt + d, 1);
    nbr[offs[d] + pd] = s;
    int ps = atomicAdd(cnt + s, 1);
    nbr[offs[s] + ps] = d;
  }
}

// ---- msg = h @ W + b ; one wave per row, lane j owns column j
__global__ __launch_bounds__(256) void k_gemm(const float* __restrict__ h,
                                              const float* __restrict__ W,
                                              const float* __restrict__ b,
                                              float* __restrict__ out, int nrows) {
  const int lane = threadIdx.x & 63;
  const int wid = (blockIdx.x * 256 + threadIdx.x) >> 6;
  const int nw = (gridDim.x * 256) >> 6;
  float w[64];
#pragma unroll
  for (int k = 0; k < 64; ++k) w[k] = W[k * 64 + lane];
  const float bias = b[lane];
  for (int r = wid; r < nrows; r += nw) {
    const float4* hr = reinterpret_cast<const float4*>(h + (size_t)r * 64);
    float acc = bias;
#pragma unroll
    for (int k4 = 0; k4 < 16; ++k4) {
      float4 hv = hr[k4];
      acc = fmaf(hv.x, w[4 * k4 + 0], acc);
      acc = fmaf(hv.y, w[4 * k4 + 1], acc);
      acc = fmaf(hv.z, w[4 * k4 + 2], acc);
      acc = fmaf(hv.w, w[4 * k4 + 3], acc);
    }
    out[(size_t)r * 64 + lane] = acc;
  }
}

// ---- out = h @ W0 + b0 + gather(msg)/deg ; optional fused LayerNorm + ReLU
template <bool LN>
__global__ __launch_bounds__(256) void k_conv_out(const float* __restrict__ h,
                                                  const float* __restrict__ W,
                                                  const float* __restrict__ b,
                                                  const float* __restrict__ msg,
                                                  const int* __restrict__ offs,
                                                  const int* __restrict__ nbr,
                                                  const float* __restrict__ gamma,
                                                  const float* __restrict__ beta,
                                                  float* __restrict__ out, int nrows) {
  const int lane = threadIdx.x & 63;
  const int wid = (blockIdx.x * 256 + threadIdx.x) >> 6;
  const int nw = (gridDim.x * 256) >> 6;
  float w[64];
#pragma unroll
  for (int k = 0; k < 64; ++k) w[k] = W[k * 64 + lane];
  const float bias = b[lane];
  float gm = 1.0f, bt = 0.0f;
  if (LN) { gm = gamma[lane]; bt = beta[lane]; }
  for (int r = wid; r < nrows; r += nw) {
    const float4* hr = reinterpret_cast<const float4*>(h + (size_t)r * 64);
    float acc = bias;
#pragma unroll
    for (int k4 = 0; k4 < 16; ++k4) {
      float4 hv = hr[k4];  // wave-uniform -> broadcast
      acc = fmaf(hv.x, w[4 * k4 + 0], acc);
      acc = fmaf(hv.y, w[4 * k4 + 1], acc);
      acc = fmaf(hv.z, w[4 * k4 + 2], acc);
      acc = fmaf(hv.w, w[4 * k4 + 3], acc);
    }
    // gather neighbors' msg rows (coalesced 256B row reads, indices broadcast)
    const int n0 = offs[r], n1 = offs[r + 1];
    float ag = 0.0f;
    int j = n0;
    for (; j + 4 <= n1; j += 4) {
      const int i0 = nbr[j + 0], i1 = nbr[j + 1], i2 = nbr[j + 2], i3 = nbr[j + 3];
      const float m0 = msg[(size_t)i0 * 64 + lane];
      const float m1 = msg[(size_t)i1 * 64 + lane];
      const float m2 = msg[(size_t)i2 * 64 + lane];
      const float m3 = msg[(size_t)i3 * 64 + lane];
      ag += (m0 + m1) + (m2 + m3);
    }
    for (; j < n1; ++j) ag += msg[(size_t)nbr[j] * 64 + lane];
    const float rdeg = 1.0f / fmaxf((float)(n1 - n0), 1.0f);
    float val = fmaf(ag, rdeg, acc);
    if (LN) {
      float s = val;
#pragma unroll
      for (int off = 32; off > 0; off >>= 1) s += __shfl_xor(s, off, 64);
      const float mu = s * (1.0f / 64.0f);
      const float dv = val - mu;
      float v2 = dv * dv;
#pragma unroll
      for (int off = 32; off > 0; off >>= 1) v2 += __shfl_xor(v2, off, 64);
      const float var = v2 * (1.0f / 64.0f);
      val = fmaxf(fmaf(dv * rsqrtf(var + 1e-5f), gm, bt), 0.0f);
    }
    out[(size_t)r * 64 + lane] = val;
  }
}

extern "C" void kernel_launch(void* const* d_in, const int* in_sizes, int n_in,
                              void* d_out, int out_size, void* d_ws, size_t ws_size,
                              hipStream_t stream) {
  const float* vert = (const float*)d_in[0];
  const int* edges = (const int*)d_in[1];
  const float* W0 = (const float*)d_in[2];
  const float* b0 = (const float*)d_in[3];
  const float* W1 = (const float*)d_in[4];
  const float* b1 = (const float*)d_in[5];
  const float* lng = (const float*)d_in[6];
  const float* lnb = (const float*)d_in[7];
  float* out = (float*)d_out;

  const size_t HB = (size_t)NN * D_ * sizeof(float);          // 25.6 MB
  float* hbuf = (float*)d_ws;                                  // h buffer
  int* nbr = (int*)((char*)d_ws + HB);                         // 2*NE ints (12.8 MB)
  int* offs = (int*)((char*)d_ws + HB + (size_t)2 * NE * 4);   // NN+1 ints
  int* cnt = offs + (NN + 1);                                  // NN ints
  float* msg = out;                                            // d_out doubles as msg

  // ---- CSR build (once)
  hipMemsetAsync(cnt, 0, NN * sizeof(int), stream);
  k_count<<<(2 * NE + 255) / 256, 256, 0, stream>>>(edges, cnt, 2 * NE);
  k_scan<<<1, 1024, 0, stream>>>(cnt, offs, NN);
  hipMemsetAsync(cnt, 0, NN * sizeof(int), stream);
  k_fill<<<(NE + 255) / 256, 256, 0, stream>>>(edges, offs, cnt, nbr, NE);

  const int GB = 2048;

  // layer 0: h = vert (const input), out -> hbuf
  k_gemm<<<GB, 256, 0, stream>>>(vert, W1, b1, msg, NN);
  k_conv_out<true><<<GB, 256, 0, stream>>>(vert, W0, b0, msg, offs, nbr,
                                           lng, lnb, hbuf, NN);
  // layer 1: in-place h update (each wave reads only its own row before writing)
  k_gemm<<<GB, 256, 0, stream>>>(hbuf, W1 + 4096, b1 + 64, msg, NN);
  k_conv_out<true><<<GB, 256, 0, stream>>>(hbuf, W0 + 4096, b0 + 64, msg, offs, nbr,
                                           lng + 64, lnb + 64, hbuf, NN);
  // layer 2: msg still in d_out; write result to hbuf, then d2d copy to d_out
  k_gemm<<<GB, 256, 0, stream>>>(hbuf, W1 + 8192, b1 + 128, msg, NN);
  k_conv_out<false><<<GB, 256, 0, stream>>>(hbuf, W0 + 8192, b0 + 128, msg, offs, nbr,
                                            nullptr, nullptr, hbuf, NN);
  hipMemcpyAsync(out, hbuf, HB, hipMemcpyDeviceToDevice, stream);
}

// Round 3
// 1423.632 us; speedup vs baseline: 1.8064x; 1.0102x over previous
//
#include <hip/hip_runtime.h>
#include <hip/hip_bf16.h>

constexpr int D_ = 64;
constexpr int NN = 100000;
constexpr int NE = 1600000;

// ---- count endpoint occurrences (flat edges = 2*NE node ids)
__global__ __launch_bounds__(256) void k_count(const int* __restrict__ ef,
                                               int* __restrict__ cnt, int n) {
  int i = blockIdx.x * 256 + threadIdx.x;
  if (i < n) atomicAdd(cnt + ef[i], 1);
}

// ---- single-workgroup exclusive prefix scan over NN counts -> offs[0..NN]
__global__ __launch_bounds__(1024) void k_scan(const int* __restrict__ cnt,
                                               int* __restrict__ offs, int n) {
  __shared__ int sd[1024];
  __shared__ int running;
  const int tid = threadIdx.x;
  if (tid == 0) running = 0;
  __syncthreads();
  for (int base = 0; base < n; base += 1024) {
    int i = base + tid;
    int v = (i < n) ? cnt[i] : 0;
    sd[tid] = v;
    __syncthreads();
    for (int off = 1; off < 1024; off <<= 1) {
      int t = (tid >= off) ? sd[tid - off] : 0;
      __syncthreads();
      sd[tid] += t;
      __syncthreads();
    }
    int ex = running + sd[tid] - v;
    if (i < n) offs[i] = ex;
    int tot = sd[1023];
    __syncthreads();
    if (tid == 0) running += tot;
    __syncthreads();
  }
  if (tid == 0) offs[n] = running;
}

// ---- fill neighbor lists: for each edge, d's list gets s and s's list gets d
__global__ __launch_bounds__(256) void k_fill(const int* __restrict__ edges,
                                              const int* __restrict__ offs,
                                              int* __restrict__ cnt,
                                              int* __restrict__ nbr, int ne) {
  int e = blockIdx.x * 256 + threadIdx.x;
  if (e < ne) {
    int s = edges[2 * e];
    int d = edges[2 * e + 1];
    int pd = atomicAdd(cnt + d, 1);
    nbr[offs[d] + pd] = s;
    int ps = atomicAdd(cnt + s, 1);
    nbr[offs[s] + ps] = d;
  }
}

// ---- msg = bf16(h @ W + b) ; one wave per row, lane j owns column j
__global__ __launch_bounds__(256) void k_gemm(const float* __restrict__ h,
                                              const float* __restrict__ W,
                                              const float* __restrict__ b,
                                              __hip_bfloat16* __restrict__ out,
                                              int nrows) {
  const int lane = threadIdx.x & 63;
  const int wid = (blockIdx.x * 256 + threadIdx.x) >> 6;
  const int nw = (gridDim.x * 256) >> 6;
  float w[64];
#pragma unroll
  for (int k = 0; k < 64; ++k) w[k] = W[k * 64 + lane];
  const float bias = b[lane];
  for (int r = wid; r < nrows; r += nw) {
    const float4* hr = reinterpret_cast<const float4*>(h + (size_t)r * 64);
    float acc = bias;
#pragma unroll
    for (int k4 = 0; k4 < 16; ++k4) {
      float4 hv = hr[k4];  // wave-uniform -> broadcast
      acc = fmaf(hv.x, w[4 * k4 + 0], acc);
      acc = fmaf(hv.y, w[4 * k4 + 1], acc);
      acc = fmaf(hv.z, w[4 * k4 + 2], acc);
      acc = fmaf(hv.w, w[4 * k4 + 3], acc);
    }
    out[(size_t)r * 64 + lane] = __float2bfloat16(acc);
  }
}

// ---- out = h @ W0 + b0 + gather(msg)/deg ; optional fused LayerNorm + ReLU
template <bool LN>
__global__ __launch_bounds__(256) void k_conv_out(const float* __restrict__ h,
                                                  const float* __restrict__ W,
                                                  const float* __restrict__ b,
                                                  const __hip_bfloat16* __restrict__ msg,
                                                  const int* __restrict__ offs,
                                                  const int* __restrict__ nbr,
                                                  const float* __restrict__ gamma,
                                                  const float* __restrict__ beta,
                                                  float* __restrict__ out, int nrows) {
  const int lane = threadIdx.x & 63;
  const int wid = (blockIdx.x * 256 + threadIdx.x) >> 6;
  const int nw = (gridDim.x * 256) >> 6;
  float w[64];
#pragma unroll
  for (int k = 0; k < 64; ++k) w[k] = W[k * 64 + lane];
  const float bias = b[lane];
  float gm = 1.0f, bt = 0.0f;
  if (LN) { gm = gamma[lane]; bt = beta[lane]; }
  for (int r = wid; r < nrows; r += nw) {
    const float4* hr = reinterpret_cast<const float4*>(h + (size_t)r * 64);
    float acc = bias;
#pragma unroll
    for (int k4 = 0; k4 < 16; ++k4) {
      float4 hv = hr[k4];
      acc = fmaf(hv.x, w[4 * k4 + 0], acc);
      acc = fmaf(hv.y, w[4 * k4 + 1], acc);
      acc = fmaf(hv.z, w[4 * k4 + 2], acc);
      acc = fmaf(hv.w, w[4 * k4 + 3], acc);
    }
    // gather neighbors' bf16 msg rows: 8-wide unroll -> 8 outstanding 128B loads
    const int n0 = offs[r], n1 = offs[r + 1];
    float ag = 0.0f;
    int j = n0;
    for (; j + 8 <= n1; j += 8) {
      int idx[8];
#pragma unroll
      for (int u = 0; u < 8; ++u) idx[u] = nbr[j + u];
      float m[8];
#pragma unroll
      for (int u = 0; u < 8; ++u)
        m[u] = __bfloat162float(msg[(size_t)idx[u] * 64 + lane]);
      ag += ((m[0] + m[1]) + (m[2] + m[3])) + ((m[4] + m[5]) + (m[6] + m[7]));
    }
    for (; j < n1; ++j) ag += __bfloat162float(msg[(size_t)nbr[j] * 64 + lane]);
    const float rdeg = 1.0f / fmaxf((float)(n1 - n0), 1.0f);
    float val = fmaf(ag, rdeg, acc);
    if (LN) {
      float s = val;
#pragma unroll
      for (int off = 32; off > 0; off >>= 1) s += __shfl_xor(s, off, 64);
      const float mu = s * (1.0f / 64.0f);
      const float dv = val - mu;
      float v2 = dv * dv;
#pragma unroll
      for (int off = 32; off > 0; off >>= 1) v2 += __shfl_xor(v2, off, 64);
      const float var = v2 * (1.0f / 64.0f);
      val = fmaxf(fmaf(dv * rsqrtf(var + 1e-5f), gm, bt), 0.0f);
    }
    out[(size_t)r * 64 + lane] = val;
  }
}

extern "C" void kernel_launch(void* const* d_in, const int* in_sizes, int n_in,
                              void* d_out, int out_size, void* d_ws, size_t ws_size,
                              hipStream_t stream) {
  const float* vert = (const float*)d_in[0];
  const int* edges = (const int*)d_in[1];
  const float* W0 = (const float*)d_in[2];
  const float* b0 = (const float*)d_in[3];
  const float* W1 = (const float*)d_in[4];
  const float* b1 = (const float*)d_in[5];
  const float* lng = (const float*)d_in[6];
  const float* lnb = (const float*)d_in[7];
  float* out = (float*)d_out;

  const size_t HB = (size_t)NN * D_ * sizeof(float);          // 25.6 MB
  float* hbuf = (float*)d_ws;                                  // h buffer
  int* nbr = (int*)((char*)d_ws + HB);                         // 2*NE ints (12.8 MB)
  int* offs = (int*)((char*)d_ws + HB + (size_t)2 * NE * 4);   // NN+1 ints
  int* cnt = offs + (NN + 1);                                  // NN ints
  __hip_bfloat16* msg = (__hip_bfloat16*)out;                  // 12.8 MB in d_out

  // ---- CSR build (once)
  hipMemsetAsync(cnt, 0, NN * sizeof(int), stream);
  k_count<<<(2 * NE + 255) / 256, 256, 0, stream>>>(edges, cnt, 2 * NE);
  k_scan<<<1, 1024, 0, stream>>>(cnt, offs, NN);
  hipMemsetAsync(cnt, 0, NN * sizeof(int), stream);
  k_fill<<<(NE + 255) / 256, 256, 0, stream>>>(edges, offs, cnt, nbr, NE);

  const int GB = 2048;

  // layer 0
  k_gemm<<<GB, 256, 0, stream>>>(vert, W1, b1, msg, NN);
  k_conv_out<true><<<GB, 256, 0, stream>>>(vert, W0, b0, msg, offs, nbr,
                                           lng, lnb, hbuf, NN);
  // layer 1 (in-place h update: each wave reads only its own row before writing)
  k_gemm<<<GB, 256, 0, stream>>>(hbuf, W1 + 4096, b1 + 64, msg, NN);
  k_conv_out<true><<<GB, 256, 0, stream>>>(hbuf, W0 + 4096, b0 + 64, msg, offs, nbr,
                                           lng + 64, lnb + 64, hbuf, NN);
  // layer 2: msg aliases d_out -> write result to hbuf, then d2d copy
  k_gemm<<<GB, 256, 0, stream>>>(hbuf, W1 + 8192, b1 + 128, msg, NN);
  k_conv_out<false><<<GB, 256, 0, stream>>>(hbuf, W0 + 8192, b0 + 128, msg, offs, nbr,
                                            nullptr, nullptr, hbuf, NN);
  hipMemcpyAsync(out, hbuf, HB, hipMemcpyDeviceToDevice, stream);
}